// Round 1
// baseline (386.372 us; speedup 1.0000x reference)
//
#include <hip/hip_runtime.h>
#include <stdint.h>

#define SEQ 4096
#define DM 768
#define NH 12
#define HD 64

typedef unsigned short u16;
typedef short short8 __attribute__((ext_vector_type(8)));
typedef float floatx4 __attribute__((ext_vector_type(4)));
typedef u16 u16x4 __attribute__((ext_vector_type(4)));

__device__ inline u16 f2b(float f) {
  union { float f; uint32_t u; } v; v.f = f;
  uint32_t u = v.u;
  return (u16)((u + 0x7fffu + ((u >> 16) & 1u)) >> 16);
}

__device__ inline void load_lds16(const void* g, void* l) {
  __builtin_amdgcn_global_load_lds(
      (const __attribute__((address_space(1))) uint32_t*)g,
      (__attribute__((address_space(3))) uint32_t*)l, 16, 0, 0);
}

// ---------------- fp32 -> bf16 conversion of X and the 4 weight matrices ----
__global__ __launch_bounds__(256) void convert_all(
    const float* __restrict__ X, const float* __restrict__ Wq,
    const float* __restrict__ Wk, const float* __restrict__ Wv,
    const float* __restrict__ Wo,
    u16* __restrict__ Xb, u16* __restrict__ Wqb, u16* __restrict__ Wkb,
    u16* __restrict__ Wvb, u16* __restrict__ Wob) {
  int t = blockIdx.x * 256 + threadIdx.x;   // each thread: 4 floats
  const int NX = SEQ * DM / 4;              // 786432
  const int NW = DM * DM / 4;               // 147456
  const float* src; u16* dst; int off;
  if (t < NX)               { src = X;  dst = Xb;  off = t; }
  else if (t < NX + NW)     { src = Wq; dst = Wqb; off = t - NX; }
  else if (t < NX + 2 * NW) { src = Wk; dst = Wkb; off = t - NX - NW; }
  else if (t < NX + 3 * NW) { src = Wv; dst = Wvb; off = t - NX - 2 * NW; }
  else if (t < NX + 4 * NW) { src = Wo; dst = Wob; off = t - NX - 3 * NW; }
  else return;
  float4 v = *(const float4*)(src + (size_t)off * 4);
  u16x4 o; o[0] = f2b(v.x); o[1] = f2b(v.y); o[2] = f2b(v.z); o[3] = f2b(v.w);
  *(u16x4*)(dst + (size_t)off * 4) = o;
}

// ---------------- QKV projection GEMM -----------------------------
// C[s,j] = sum_k X[s,k] * W[j,k] + b[j]   (nn.Linear: X @ W^T + b)
// 128x128 tile, BK=32, 256 threads (4 waves, each 64x64 via 4x4 16x16 tiles)
// output written bf16, head-major: out[h][s][d], h = j/64, d = j%64
__global__ __launch_bounds__(256) void gemm_qkv(
    const u16* __restrict__ Xb,
    const u16* __restrict__ Wqb, const u16* __restrict__ Wkb,
    const u16* __restrict__ Wvb,
    const float* __restrict__ bq, const float* __restrict__ bk,
    const float* __restrict__ bv,
    u16* __restrict__ Qh, u16* __restrict__ Kh, u16* __restrict__ Vh) {
  const u16* W; const float* bias; u16* out;
  if (blockIdx.z == 0)      { W = Wqb; bias = bq; out = Qh; }
  else if (blockIdx.z == 1) { W = Wkb; bias = bk; out = Kh; }
  else                      { W = Wvb; bias = bv; out = Vh; }

  __shared__ u16 As[128 * 32];
  __shared__ u16 Bs[128 * 32];

  const int tid = threadIdx.x;
  const int wave = tid >> 6, lane = tid & 63;
  const int g = lane >> 4, ln = lane & 15;
  const int m0 = blockIdx.y * 128, n0 = blockIdx.x * 128;
  const int wm = (wave & 1) * 64, wn = (wave >> 1) * 64;
  const int lr = lane >> 2;          // row within 16-row staging unit
  const int lc = (lane & 3) * 8;     // k-offset within 32

  floatx4 acc[4][4] = {};

  for (int k0 = 0; k0 < DM; k0 += 32) {
    __syncthreads();
#pragma unroll
    for (int i = 0; i < 2; ++i) {
      int u = wave * 2 + i;
      const u16* ga = Xb + (size_t)(m0 + u * 16 + lr) * DM + k0 + lc;
      load_lds16(ga, As + u * 512);
      const u16* gb = W + (size_t)(n0 + u * 16 + lr) * DM + k0 + lc;
      load_lds16(gb, Bs + u * 512);
    }
    __syncthreads();
    short8 af[4], bf[4];
#pragma unroll
    for (int mi = 0; mi < 4; ++mi)
      af[mi] = *(const short8*)(As + (wm + mi * 16 + ln) * 32 + g * 8);
#pragma unroll
    for (int ni = 0; ni < 4; ++ni)
      bf[ni] = *(const short8*)(Bs + (wn + ni * 16 + ln) * 32 + g * 8);
#pragma unroll
    for (int mi = 0; mi < 4; ++mi)
#pragma unroll
      for (int ni = 0; ni < 4; ++ni)
        acc[mi][ni] = __builtin_amdgcn_mfma_f32_16x16x32_bf16(
            af[mi], bf[ni], acc[mi][ni], 0, 0, 0);
  }

  // epilogue: C row = wm+mi*16 + g*4 + r, col = wn+ni*16 + ln
#pragma unroll
  for (int mi = 0; mi < 4; ++mi) {
    int row = m0 + wm + mi * 16 + g * 4;
#pragma unroll
    for (int ni = 0; ni < 4; ++ni) {
      int col = n0 + wn + ni * 16 + ln;
      int hh = col >> 6, dd = col & 63;
      float b = bias[col];
      u16* op = out + ((size_t)hh * SEQ) * HD + dd;
#pragma unroll
      for (int r = 0; r < 4; ++r)
        op[(size_t)(row + r) * HD] = f2b(acc[mi][ni][r] + b);
    }
  }
}

// ---------------- flash attention (causal) -------------------------
// block = (qb, h): 64 query rows, 4 waves x 16 rows. keys iterated 64 at a time.
__global__ __launch_bounds__(256) void attn(
    const u16* __restrict__ Qh, const u16* __restrict__ Kh,
    const u16* __restrict__ Vh, u16* __restrict__ Ob) {
  const int qb = (SEQ / 64 - 1) - blockIdx.x;  // big blocks first
  const int h = blockIdx.y;
  const int tid = threadIdx.x, wave = tid >> 6, lane = tid & 63;
  const int g = lane >> 4, ln = lane & 15;
  const int q0 = qb * 64;

  __shared__ u16 Ks[64 * 64];      // [key][d]
  __shared__ u16 Vt[64 * 64];      // [d][key]  (transposed)
  __shared__ u16 Ps[4][16 * 64];   // per-wave P staging [q][key]

  // Q fragments: A[m=ln][k = g*8+j (+32)]
  const u16* Qbase = Qh + ((size_t)h * SEQ + q0 + wave * 16 + ln) * HD;
  short8 aq0 = *(const short8*)(Qbase + g * 8);
  short8 aq1 = *(const short8*)(Qbase + g * 8 + 32);

  floatx4 o_acc[4] = {};
  float m_i[4], l_i[4];
#pragma unroll
  for (int r = 0; r < 4; ++r) { m_i[r] = -1e30f; l_i[r] = 0.f; }

  for (int kb = 0; kb <= qb; ++kb) {
    __syncthreads();
    // stage K rows (64x64 bf16 = 8KB) via async copy
#pragma unroll
    for (int i = 0; i < 2; ++i) {
      int u = wave * 2 + i;
      const u16* gk = Kh + ((size_t)h * SEQ + kb * 64 + u * 8 + (lane >> 3)) * HD
                      + (lane & 7) * 8;
      load_lds16(gk, Ks + u * 512);
    }
    // stage V transposed: lane = key, each wave covers 16 dims
    {
      const u16* gv = Vh + ((size_t)h * SEQ + kb * 64 + lane) * HD;
#pragma unroll
      for (int i = 0; i < 2; ++i) {
        int d0 = wave * 16 + i * 8;
        short8 v = *(const short8*)(gv + d0);
#pragma unroll
        for (int j = 0; j < 8; ++j)
          Vt[(d0 + j) * 64 + lane] = (u16)v[j];
      }
    }
    __syncthreads();

    // S = Q K^T  (16 q-rows x 64 keys per wave)
    floatx4 s_acc[4] = {};
#pragma unroll
    for (int nt = 0; nt < 4; ++nt) {
      short8 bk0 = *(const short8*)(Ks + (nt * 16 + ln) * 64 + g * 8);
      short8 bk1 = *(const short8*)(Ks + (nt * 16 + ln) * 64 + g * 8 + 32);
      s_acc[nt] = __builtin_amdgcn_mfma_f32_16x16x32_bf16(aq0, bk0, s_acc[nt], 0, 0, 0);
      s_acc[nt] = __builtin_amdgcn_mfma_f32_16x16x32_bf16(aq1, bk1, s_acc[nt], 0, 0, 0);
    }

    // online softmax (per C-layout row = g*4 + r)
    float p[4][4];  // [nt][r]
    const int rowg0 = q0 + wave * 16 + g * 4;
    const bool diag = (kb == qb);
#pragma unroll
    for (int r = 0; r < 4; ++r) {
      float mx = -1e30f;
#pragma unroll
      for (int nt = 0; nt < 4; ++nt) {
        float s = s_acc[nt][r] * 0.125f;
        int colg = kb * 64 + nt * 16 + ln;
        if (diag && colg > rowg0 + r) s = -1e30f;
        p[nt][r] = s;
        mx = fmaxf(mx, s);
      }
#pragma unroll
      for (int m = 1; m < 16; m <<= 1) mx = fmaxf(mx, __shfl_xor(mx, m));
      float mnew = fmaxf(m_i[r], mx);
      float alpha = __expf(m_i[r] - mnew);
      m_i[r] = mnew;
      float rs = 0.f;
#pragma unroll
      for (int nt = 0; nt < 4; ++nt) {
        float e = __expf(p[nt][r] - mnew);
        p[nt][r] = e;
        rs += e;
      }
#pragma unroll
      for (int m = 1; m < 16; m <<= 1) rs += __shfl_xor(rs, m);
      l_i[r] = l_i[r] * alpha + rs;
#pragma unroll
      for (int nt = 0; nt < 4; ++nt) o_acc[nt][r] *= alpha;
    }

    // P: C-layout -> LDS (row-major [q][key]) -> A-layout
#pragma unroll
    for (int nt = 0; nt < 4; ++nt)
#pragma unroll
      for (int r = 0; r < 4; ++r)
        Ps[wave][(g * 4 + r) * 64 + nt * 16 + ln] = f2b(p[nt][r]);
    __syncthreads();

    // O += P V : A[m=ln][k=ks*32+g*8+j], B[k][n=d] from Vt rows
#pragma unroll
    for (int ks = 0; ks < 2; ++ks) {
      short8 ap = *(const short8*)(&Ps[wave][ln * 64 + ks * 32 + g * 8]);
#pragma unroll
      for (int nt = 0; nt < 4; ++nt) {
        short8 bv = *(const short8*)(Vt + (nt * 16 + ln) * 64 + ks * 32 + g * 8);
        o_acc[nt] = __builtin_amdgcn_mfma_f32_16x16x32_bf16(ap, bv, o_acc[nt], 0, 0, 0);
      }
    }
  }

  // epilogue: O[s][h*64 + d] bf16
#pragma unroll
  for (int r = 0; r < 4; ++r) {
    float inv = 1.f / l_i[r];
    int row = q0 + wave * 16 + g * 4 + r;
#pragma unroll
    for (int nt = 0; nt < 4; ++nt) {
      float v = o_acc[nt][r] * inv;
      Ob[(size_t)row * DM + h * HD + nt * 16 + ln] = f2b(v);
    }
  }
}

// ---------------- output projection GEMM (fp32 out) -----------------
__global__ __launch_bounds__(256) void gemm_out(
    const u16* __restrict__ Ab, const u16* __restrict__ Wob,
    const float* __restrict__ bo, float* __restrict__ Cout) {
  __shared__ u16 As[128 * 32];
  __shared__ u16 Bs[128 * 32];

  const int tid = threadIdx.x;
  const int wave = tid >> 6, lane = tid & 63;
  const int g = lane >> 4, ln = lane & 15;
  const int m0 = blockIdx.y * 128, n0 = blockIdx.x * 128;
  const int wm = (wave & 1) * 64, wn = (wave >> 1) * 64;
  const int lr = lane >> 2;
  const int lc = (lane & 3) * 8;

  floatx4 acc[4][4] = {};

  for (int k0 = 0; k0 < DM; k0 += 32) {
    __syncthreads();
#pragma unroll
    for (int i = 0; i < 2; ++i) {
      int u = wave * 2 + i;
      const u16* ga = Ab + (size_t)(m0 + u * 16 + lr) * DM + k0 + lc;
      load_lds16(ga, As + u * 512);
      const u16* gb = Wob + (size_t)(n0 + u * 16 + lr) * DM + k0 + lc;
      load_lds16(gb, Bs + u * 512);
    }
    __syncthreads();
    short8 af[4], bf[4];
#pragma unroll
    for (int mi = 0; mi < 4; ++mi)
      af[mi] = *(const short8*)(As + (wm + mi * 16 + ln) * 32 + g * 8);
#pragma unroll
    for (int ni = 0; ni < 4; ++ni)
      bf[ni] = *(const short8*)(Bs + (wn + ni * 16 + ln) * 32 + g * 8);
#pragma unroll
    for (int mi = 0; mi < 4; ++mi)
#pragma unroll
      for (int ni = 0; ni < 4; ++ni)
        acc[mi][ni] = __builtin_amdgcn_mfma_f32_16x16x32_bf16(
            af[mi], bf[ni], acc[mi][ni], 0, 0, 0);
  }

#pragma unroll
  for (int mi = 0; mi < 4; ++mi) {
    int row = m0 + wm + mi * 16 + g * 4;
#pragma unroll
    for (int ni = 0; ni < 4; ++ni) {
      int col = n0 + wn + ni * 16 + ln;
      float b = bo[col];
#pragma unroll
      for (int r = 0; r < 4; ++r)
        Cout[(size_t)(row + r) * DM + col] = acc[mi][ni][r] + b;
    }
  }
}

extern "C" void kernel_launch(void* const* d_in, const int* in_sizes, int n_in,
                              void* d_out, int out_size, void* d_ws, size_t ws_size,
                              hipStream_t stream) {
  const float* X  = (const float*)d_in[0];
  const float* Wq = (const float*)d_in[1];
  const float* bq = (const float*)d_in[2];
  const float* Wk = (const float*)d_in[3];
  const float* bk = (const float*)d_in[4];
  const float* Wv = (const float*)d_in[5];
  const float* bv = (const float*)d_in[6];
  const float* Wo = (const float*)d_in[7];
  const float* bo = (const float*)d_in[8];
  float* out = (float*)d_out;

  char* ws = (char*)d_ws;
  u16* Xb  = (u16*)ws; ws += (size_t)SEQ * DM * 2;
  u16* Wqb = (u16*)ws; ws += (size_t)DM * DM * 2;
  u16* Wkb = (u16*)ws; ws += (size_t)DM * DM * 2;
  u16* Wvb = (u16*)ws; ws += (size_t)DM * DM * 2;
  u16* Wob = (u16*)ws; ws += (size_t)DM * DM * 2;
  u16* Qh  = (u16*)ws; ws += (size_t)NH * SEQ * HD * 2;
  u16* Kh  = (u16*)ws; ws += (size_t)NH * SEQ * HD * 2;
  u16* Vh  = (u16*)ws; ws += (size_t)NH * SEQ * HD * 2;
  u16* Ob  = (u16*)ws; ws += (size_t)SEQ * DM * 2;

  convert_all<<<5376, 256, 0, stream>>>(X, Wq, Wk, Wv, Wo, Xb, Wqb, Wkb, Wvb, Wob);

  dim3 gq(DM / 128, SEQ / 128, 3);
  gemm_qkv<<<gq, 256, 0, stream>>>(Xb, Wqb, Wkb, Wvb, bq, bk, bv, Qh, Kh, Vh);

  dim3 ga(SEQ / 64, NH);
  attn<<<ga, 256, 0, stream>>>(Qh, Kh, Vh, Ob);

  dim3 go(DM / 128, SEQ / 128);
  gemm_out<<<go, 256, 0, stream>>>(Ob, Wob, bo, out);
}

// Round 2
// 211.862 us; speedup vs baseline: 1.8237x; 1.8237x over previous
//
#include <hip/hip_runtime.h>
#include <stdint.h>

#define SEQ 4096
#define DM 768
#define NH 12
#define HD 64

typedef unsigned short u16;
typedef short short8 __attribute__((ext_vector_type(8)));
typedef float floatx4 __attribute__((ext_vector_type(4)));
typedef u16 u16x4 __attribute__((ext_vector_type(4)));

__device__ inline u16 f2b(float f) {
  union { float f; uint32_t u; } v; v.f = f;
  uint32_t u = v.u;
  return (u16)((u + 0x7fffu + ((u >> 16) & 1u)) >> 16);
}

__device__ inline void load_lds16(const void* g, void* l) {
  __builtin_amdgcn_global_load_lds(
      (const __attribute__((address_space(1))) uint32_t*)g,
      (__attribute__((address_space(3))) uint32_t*)l, 16, 0, 0);
}

// ---------------- fp32 -> bf16 conversion of X and the 4 weight matrices ----
__global__ __launch_bounds__(256) void convert_all(
    const float* __restrict__ X, const float* __restrict__ Wq,
    const float* __restrict__ Wk, const float* __restrict__ Wv,
    const float* __restrict__ Wo,
    u16* __restrict__ Xb, u16* __restrict__ Wqb, u16* __restrict__ Wkb,
    u16* __restrict__ Wvb, u16* __restrict__ Wob) {
  int t = blockIdx.x * 256 + threadIdx.x;   // each thread: 4 floats
  const int NX = SEQ * DM / 4;              // 786432
  const int NW = DM * DM / 4;               // 147456
  const float* src; u16* dst; int off;
  if (t < NX)               { src = X;  dst = Xb;  off = t; }
  else if (t < NX + NW)     { src = Wq; dst = Wqb; off = t - NX; }
  else if (t < NX + 2 * NW) { src = Wk; dst = Wkb; off = t - NX - NW; }
  else if (t < NX + 3 * NW) { src = Wv; dst = Wvb; off = t - NX - 2 * NW; }
  else if (t < NX + 4 * NW) { src = Wo; dst = Wob; off = t - NX - 3 * NW; }
  else return;
  float4 v = *(const float4*)(src + (size_t)off * 4);
  u16x4 o; o[0] = f2b(v.x); o[1] = f2b(v.y); o[2] = f2b(v.z); o[3] = f2b(v.w);
  *(u16x4*)(dst + (size_t)off * 4) = o;
}

// ---------------- QKV projection GEMM (BK=64, swizzled LDS) ----------------
// C[s,j] = sum_k X[s,k] * W[j,k] + b[j]
// Q out: [h][s][d] scaled by 0.125*log2e ; K out: [h][s][d] ; V out: [h][d][s]
__global__ __launch_bounds__(256) void gemm_qkv(
    const u16* __restrict__ Xb,
    const u16* __restrict__ Wqb, const u16* __restrict__ Wkb,
    const u16* __restrict__ Wvb,
    const float* __restrict__ bq, const float* __restrict__ bk,
    const float* __restrict__ bv,
    u16* __restrict__ Qh, u16* __restrict__ Kh, u16* __restrict__ VtG) {
  const u16* W; const float* bias;
  const int z = blockIdx.z;
  if (z == 0)      { W = Wqb; bias = bq; }
  else if (z == 1) { W = Wkb; bias = bk; }
  else             { W = Wvb; bias = bv; }

  __shared__ u16 As[128 * 64];
  __shared__ u16 Bs[128 * 64];

  const int tid = threadIdx.x;
  const int wave = tid >> 6, lane = tid & 63;
  const int g = lane >> 4, ln = lane & 15;
  const int m0 = blockIdx.y * 128, n0 = blockIdx.x * 128;
  const int wm = (wave & 1) * 64, wn = (wave >> 1) * 64;
  const int srow = lane >> 3;                 // 0..7
  const int schunk = (lane & 7) ^ srow;       // swizzled source chunk
  const int swz = ln & 7;

  floatx4 acc[4][4] = {};

  for (int k0 = 0; k0 < DM; k0 += 64) {
    __syncthreads();
#pragma unroll
    for (int i = 0; i < 4; ++i) {
      int u = wave * 4 + i;
      load_lds16(Xb + (size_t)(m0 + u * 8 + srow) * DM + k0 + schunk * 8,
                 As + u * 512);
      load_lds16(W + (size_t)(n0 + u * 8 + srow) * DM + k0 + schunk * 8,
                 Bs + u * 512);
    }
    __syncthreads();
    short8 af[4][2], bf[4][2];
#pragma unroll
    for (int mi = 0; mi < 4; ++mi)
#pragma unroll
      for (int kh = 0; kh < 2; ++kh)
        af[mi][kh] = *(const short8*)(As + (wm + mi * 16 + ln) * 64 +
                                      ((kh * 4 + g) ^ swz) * 8);
#pragma unroll
    for (int ni = 0; ni < 4; ++ni)
#pragma unroll
      for (int kh = 0; kh < 2; ++kh)
        bf[ni][kh] = *(const short8*)(Bs + (wn + ni * 16 + ln) * 64 +
                                      ((kh * 4 + g) ^ swz) * 8);
#pragma unroll
    for (int kh = 0; kh < 2; ++kh)
#pragma unroll
      for (int mi = 0; mi < 4; ++mi)
#pragma unroll
        for (int ni = 0; ni < 4; ++ni)
          acc[mi][ni] = __builtin_amdgcn_mfma_f32_16x16x32_bf16(
              af[mi][kh], bf[ni][kh], acc[mi][ni], 0, 0, 0);
  }

  const float qscale = 0.125f * 1.44269504089f;  // softmax scale * log2(e)
  if (z == 2) {
    // V^T: out[h][d][s], contiguous in s -> 8B stores
#pragma unroll
    for (int mi = 0; mi < 4; ++mi) {
      int row = m0 + wm + mi * 16 + g * 4;   // s
#pragma unroll
      for (int ni = 0; ni < 4; ++ni) {
        int col = n0 + wn + ni * 16 + ln;    // d_model index
        float b = bias[col];
        int hh = col >> 6, dd = col & 63;
        u16x4 o;
#pragma unroll
        for (int r = 0; r < 4; ++r) o[r] = f2b(acc[mi][ni][r] + b);
        *(u16x4*)(VtG + ((size_t)(hh * 64 + dd)) * SEQ + row) = o;
      }
    }
  } else {
    u16* out = (z == 0) ? Qh : Kh;
    float cs = (z == 0) ? qscale : 1.0f;
#pragma unroll
    for (int mi = 0; mi < 4; ++mi) {
      int row = m0 + wm + mi * 16 + g * 4;
#pragma unroll
      for (int ni = 0; ni < 4; ++ni) {
        int col = n0 + wn + ni * 16 + ln;
        int hh = col >> 6, dd = col & 63;
        float b = bias[col];
        u16* op = out + ((size_t)hh * SEQ) * HD + dd;
#pragma unroll
        for (int r = 0; r < 4; ++r)
          op[(size_t)(row + r) * HD] = f2b((acc[mi][ni][r] + b) * cs);
      }
    }
  }
}

// ---------------- flash attention (causal), transposed S ------------------
// block = (h, qb): 64 q rows, 4 waves x 16 q. S^T = K Q^T so each lane owns
// one q-row (q = ln); softmax reduce = in-reg + 2 shfl. O^T = V^T P^T.
__global__ __launch_bounds__(256) void attn(
    const u16* __restrict__ Qh, const u16* __restrict__ Kh,
    const u16* __restrict__ VtG, u16* __restrict__ Ob) {
  const int h = blockIdx.x;
  const int qb = (SEQ / 64 - 1) - blockIdx.y;  // big blocks first
  const int tid = threadIdx.x, wave = tid >> 6, lane = tid & 63;
  const int g = lane >> 4, ln = lane & 15;
  const int q0 = qb * 64;
  const int srow = lane >> 3;
  const int schunk = (lane & 7) ^ srow;
  const int swz = ln & 7;

  __shared__ u16 Ks[64 * 64];       // [key][d], chunk-swizzled
  __shared__ u16 Vt[64 * 64];       // [d][key], chunk-swizzled
  __shared__ u16 Ps[4][16 * 72];    // per-wave P [q][key], padded stride 72

  // Q as B-operand fragments: lane holds Q[q=ln][k = kh*32 + g*8 + j]
  const u16* Qbase = Qh + ((size_t)h * SEQ + q0 + wave * 16 + ln) * HD;
  short8 aq[2] = { *(const short8*)(Qbase + g * 8),
                   *(const short8*)(Qbase + 32 + g * 8) };

  floatx4 oacc[4] = {};   // O^T frags: lane holds O^T[d=nt*16+g*4+r][q=ln]
  float m_i = -1e30f, l_i = 0.f;
  u16* PsW = &Ps[wave][0];

  for (int kb = 0; kb <= qb; ++kb) {
    __syncthreads();
#pragma unroll
    for (int i = 0; i < 2; ++i) {
      int u = wave * 2 + i;
      load_lds16(Kh + ((size_t)h * SEQ + kb * 64 + u * 8 + srow) * HD + schunk * 8,
                 Ks + u * 512);
      load_lds16(VtG + ((size_t)(h * 64 + u * 8 + srow)) * SEQ + kb * 64 + schunk * 8,
                 Vt + u * 512);
    }
    __syncthreads();

    // S^T = K Q^T : lane gets S^T[key=nt*16+g*4+r][q=ln]
    floatx4 st[4] = {};
#pragma unroll
    for (int kh = 0; kh < 2; ++kh)
#pragma unroll
      for (int nt = 0; nt < 4; ++nt) {
        short8 kf = *(const short8*)(Ks + (nt * 16 + ln) * 64 +
                                     ((kh * 4 + g) ^ swz) * 8);
        st[nt] = __builtin_amdgcn_mfma_f32_16x16x32_bf16(kf, aq[kh], st[nt], 0, 0, 0);
      }

    if (kb == qb) {  // causal mask on the diagonal block
      int qlocal = wave * 16 + ln;
#pragma unroll
      for (int nt = 0; nt < 4; ++nt)
#pragma unroll
        for (int r = 0; r < 4; ++r)
          if (nt * 16 + g * 4 + r > qlocal) st[nt][r] = -1e30f;
    }

    // online softmax (log2 domain; scale folded into Q)
    float mx = -1e30f;
#pragma unroll
    for (int nt = 0; nt < 4; ++nt)
#pragma unroll
      for (int r = 0; r < 4; ++r) mx = fmaxf(mx, st[nt][r]);
    mx = fmaxf(mx, __shfl_xor(mx, 16));
    mx = fmaxf(mx, __shfl_xor(mx, 32));
    float mnew = fmaxf(m_i, mx);
    float alpha = __builtin_amdgcn_exp2f(m_i - mnew);
    m_i = mnew;
    float rs = 0.f;
#pragma unroll
    for (int nt = 0; nt < 4; ++nt)
#pragma unroll
      for (int r = 0; r < 4; ++r) {
        float e = __builtin_amdgcn_exp2f(st[nt][r] - mnew);
        st[nt][r] = e;
        rs += e;
      }
    rs += __shfl_xor(rs, 16);
    rs += __shfl_xor(rs, 32);
    l_i = l_i * alpha + rs;
#pragma unroll
    for (int nt = 0; nt < 4; ++nt) oacc[nt] *= alpha;

    // P -> LDS (per-wave, same-wave in-order DS, no barrier)
#pragma unroll
    for (int nt = 0; nt < 4; ++nt) {
      u16x4 pk;
#pragma unroll
      for (int r = 0; r < 4; ++r) pk[r] = f2b(st[nt][r]);
      *(u16x4*)(PsW + ln * 72 + nt * 16 + g * 4) = pk;
    }

    // O^T += V^T P^T
#pragma unroll
    for (int ks = 0; ks < 2; ++ks) {
      short8 ap = *(const short8*)(PsW + ln * 72 + ks * 32 + g * 8);
#pragma unroll
      for (int nt = 0; nt < 4; ++nt) {
        short8 vf = *(const short8*)(Vt + (nt * 16 + ln) * 64 +
                                     ((ks * 4 + g) ^ swz) * 8);
        oacc[nt] = __builtin_amdgcn_mfma_f32_16x16x32_bf16(vf, ap, oacc[nt], 0, 0, 0);
      }
    }
  }

  // epilogue: O[q][h*64+d], contiguous in r -> 8B stores
  float inv = 1.f / l_i;
  int row = q0 + wave * 16 + ln;
#pragma unroll
  for (int nt = 0; nt < 4; ++nt) {
    u16x4 o;
#pragma unroll
    for (int r = 0; r < 4; ++r) o[r] = f2b(oacc[nt][r] * inv);
    *(u16x4*)(Ob + (size_t)row * DM + h * HD + nt * 16 + g * 4) = o;
  }
}

// ---------------- output projection GEMM (fp32 out, BK=64 swizzled) --------
__global__ __launch_bounds__(256) void gemm_out(
    const u16* __restrict__ Ab, const u16* __restrict__ Wob,
    const float* __restrict__ bo, float* __restrict__ Cout) {
  __shared__ u16 As[128 * 64];
  __shared__ u16 Bs[128 * 64];

  const int tid = threadIdx.x;
  const int wave = tid >> 6, lane = tid & 63;
  const int g = lane >> 4, ln = lane & 15;
  const int m0 = blockIdx.y * 128, n0 = blockIdx.x * 128;
  const int wm = (wave & 1) * 64, wn = (wave >> 1) * 64;
  const int srow = lane >> 3;
  const int schunk = (lane & 7) ^ srow;
  const int swz = ln & 7;

  floatx4 acc[4][4] = {};

  for (int k0 = 0; k0 < DM; k0 += 64) {
    __syncthreads();
#pragma unroll
    for (int i = 0; i < 4; ++i) {
      int u = wave * 4 + i;
      load_lds16(Ab + (size_t)(m0 + u * 8 + srow) * DM + k0 + schunk * 8,
                 As + u * 512);
      load_lds16(Wob + (size_t)(n0 + u * 8 + srow) * DM + k0 + schunk * 8,
                 Bs + u * 512);
    }
    __syncthreads();
    short8 af[4][2], bf[4][2];
#pragma unroll
    for (int mi = 0; mi < 4; ++mi)
#pragma unroll
      for (int kh = 0; kh < 2; ++kh)
        af[mi][kh] = *(const short8*)(As + (wm + mi * 16 + ln) * 64 +
                                      ((kh * 4 + g) ^ swz) * 8);
#pragma unroll
    for (int ni = 0; ni < 4; ++ni)
#pragma unroll
      for (int kh = 0; kh < 2; ++kh)
        bf[ni][kh] = *(const short8*)(Bs + (wn + ni * 16 + ln) * 64 +
                                      ((kh * 4 + g) ^ swz) * 8);
#pragma unroll
    for (int kh = 0; kh < 2; ++kh)
#pragma unroll
      for (int mi = 0; mi < 4; ++mi)
#pragma unroll
        for (int ni = 0; ni < 4; ++ni)
          acc[mi][ni] = __builtin_amdgcn_mfma_f32_16x16x32_bf16(
              af[mi][kh], bf[ni][kh], acc[mi][ni], 0, 0, 0);
  }

#pragma unroll
  for (int mi = 0; mi < 4; ++mi) {
    int row = m0 + wm + mi * 16 + g * 4;
#pragma unroll
    for (int ni = 0; ni < 4; ++ni) {
      int col = n0 + wn + ni * 16 + ln;
      float b = bo[col];
#pragma unroll
      for (int r = 0; r < 4; ++r)
        Cout[(size_t)(row + r) * DM + col] = acc[mi][ni][r] + b;
    }
  }
}

extern "C" void kernel_launch(void* const* d_in, const int* in_sizes, int n_in,
                              void* d_out, int out_size, void* d_ws, size_t ws_size,
                              hipStream_t stream) {
  const float* X  = (const float*)d_in[0];
  const float* Wq = (const float*)d_in[1];
  const float* bq = (const float*)d_in[2];
  const float* Wk = (const float*)d_in[3];
  const float* bk = (const float*)d_in[4];
  const float* Wv = (const float*)d_in[5];
  const float* bv = (const float*)d_in[6];
  const float* Wo = (const float*)d_in[7];
  const float* bo = (const float*)d_in[8];
  float* out = (float*)d_out;

  char* ws = (char*)d_ws;
  u16* Xb  = (u16*)ws; ws += (size_t)SEQ * DM * 2;
  u16* Wqb = (u16*)ws; ws += (size_t)DM * DM * 2;
  u16* Wkb = (u16*)ws; ws += (size_t)DM * DM * 2;
  u16* Wvb = (u16*)ws; ws += (size_t)DM * DM * 2;
  u16* Wob = (u16*)ws; ws += (size_t)DM * DM * 2;
  u16* Qh  = (u16*)ws; ws += (size_t)NH * SEQ * HD * 2;
  u16* Kh  = (u16*)ws; ws += (size_t)NH * SEQ * HD * 2;
  u16* VtG = (u16*)ws; ws += (size_t)NH * SEQ * HD * 2;   // [h][d][s]
  u16* Ob  = (u16*)ws; ws += (size_t)SEQ * DM * 2;

  convert_all<<<5376, 256, 0, stream>>>(X, Wq, Wk, Wv, Wo, Xb, Wqb, Wkb, Wvb, Wob);

  dim3 gq(DM / 128, SEQ / 128, 3);
  gemm_qkv<<<gq, 256, 0, stream>>>(Xb, Wqb, Wkb, Wvb, bq, bk, bv, Qh, Kh, VtG);

  dim3 ga(NH, SEQ / 64);
  attn<<<ga, 256, 0, stream>>>(Qh, Kh, VtG, Ob);

  dim3 go(DM / 128, SEQ / 128);
  gemm_out<<<go, 256, 0, stream>>>(Ob, Wob, bo, out);
}